// Round 1
// baseline (1123.933 us; speedup 1.0000x reference)
//
#include <hip/hip_runtime.h>

typedef _Float16 f16;
typedef _Float16 f16x8 __attribute__((ext_vector_type(8)));
typedef float    f32x4 __attribute__((ext_vector_type(4)));

#define MFMA16(a,b,c) __builtin_amdgcn_mfma_f32_16x16x32_f16((a),(b),(c),0,0,0)

static __device__ __forceinline__ float sigm(float x){ return 1.0f/(1.0f + __expf(-x)); }

// ---------------- workspace layout (bytes) ----------------
static constexpr size_t OFF_WSE_P  = 0;
static constexpr size_t OFF_WSD_P  = OFF_WSE_P  + (size_t)8192*256*2;
static constexpr size_t OFF_WIHE_P = OFF_WSD_P  + (size_t)8192*256*2;
static constexpr size_t OFF_WIHD_P = OFF_WIHE_P + (size_t)256*1024*2;
static constexpr size_t OFF_WHHE_P = OFF_WIHD_P + (size_t)256*1024*2;
static constexpr size_t OFF_WHHD_P = OFF_WHHE_P + (size_t)256*1024*2;
static constexpr size_t OFF_W3E    = OFF_WHHD_P + (size_t)256*1024*2;
static constexpr size_t OFF_W3D    = OFF_W3E   + (size_t)3*1024*4;
static constexpr size_t OFF_W2WO   = OFF_W3D   + (size_t)3*1024*4;
static constexpr size_t OFF_BIASE  = OFF_W2WO  + (size_t)256*3*4;
static constexpr size_t OFF_BIASD  = OFF_BIASE + (size_t)1024*4;
static constexpr size_t OFF_B2WO   = OFF_BIASD + (size_t)1024*4;
static constexpr size_t OFF_SALE   = OFF_B2WO  + 256;
static constexpr size_t OFF_SALD   = OFF_SALE  + (size_t)5120*256*2;
static constexpr size_t OFF_PREGE  = OFF_SALD  + (size_t)25600*256*2;
static constexpr size_t OFF_PREGD  = OFF_PREGE + (size_t)5120*1024*2;
static constexpr size_t OFF_HFIN   = OFF_PREGD + (size_t)25600*1024*2;
static constexpr size_t OFF_CFIN   = OFF_HFIN  + (size_t)1024*256*2;

// ================= pack weights into MFMA B-fragment order =================
// layout [kfg][ctg][lane][8]; element (k,n): k = kfg*32+(l>>4)*8+i, n = ctg*16+(l&15)
__global__ void k_pack_all(const float* __restrict__ Wse, const float* __restrict__ Wsd,
                           const float* __restrict__ Wih_e, const float* __restrict__ Wih_d,
                           const float* __restrict__ Whh_e, const float* __restrict__ Whh_d,
                           f16* pWse, f16* pWsd, f16* pWih_e, f16* pWih_d,
                           f16* pWhh_e, f16* pWhh_d)
{
  int blk = blockIdx.x;
  const float* W; f16* o; int N, base;
  if      (blk < 1024) { W=Wse;   o=pWse;   N=256;  base=0; }
  else if (blk < 2048) { W=Wsd;   o=pWsd;   N=256;  base=1024; }
  else if (blk < 2176) { W=Wih_e; o=pWih_e; N=1024; base=2048; }  // rows 0..255 = sal part
  else if (blk < 2304) { W=Wih_d; o=pWih_d; N=1024; base=2176; }
  else if (blk < 2432) { W=Whh_e; o=pWhh_e; N=1024; base=2304; }
  else                 { W=Whh_d; o=pWhh_d; N=1024; base=2432; }
  int tid = (blk - base)*256 + threadIdx.x;
  int l = tid & 63;
  int nct = N >> 4;
  int ctg = (tid >> 6) % nct;
  int kfg = (tid >> 6) / nct;
  int k0  = kfg*32 + ((l>>4)<<3);
  int col = ctg*16 + (l&15);
  f16x8 v;
#pragma unroll
  for (int i=0;i<8;++i) v[i] = (f16)W[(size_t)(k0+i)*N + col];
  *(f16x8*)(o + (size_t)tid*8) = v;
}

// ================= small fused weight products =================
__global__ void k_small(const float* __restrict__ Wpe, const float* __restrict__ bpe,
                        const float* __restrict__ Wih_e, const float* __restrict__ bih_e,
                        const float* __restrict__ bhh_e,
                        const float* __restrict__ Wpd, const float* __restrict__ bpd,
                        const float* __restrict__ Wih_d, const float* __restrict__ bih_d,
                        const float* __restrict__ bhh_d,
                        const float* __restrict__ W2, const float* __restrict__ b2,
                        const float* __restrict__ Wo, const float* __restrict__ bo,
                        float* W3e, float* W3d, float* biasE, float* biasD,
                        float* W2Wo, float* b2Wo)
{
  int j = threadIdx.x;  // 1024
  {
    float s0=0,s1=0,s2=0,sb=0;
    for (int m=0;m<256;++m) {
      float wv = Wih_e[(size_t)(256+m)*1024 + j];
      s0 += Wpe[m]*wv; s1 += Wpe[256+m]*wv; s2 += Wpe[512+m]*wv; sb += bpe[m]*wv;
    }
    W3e[j]=s0; W3e[1024+j]=s1; W3e[2048+j]=s2;
    biasE[j] = bih_e[j] + bhh_e[j] + sb;
  }
  {
    float s0=0,s1=0,s2=0,sb=0;
    for (int m=0;m<256;++m) {
      float wv = Wih_d[(size_t)(256+m)*1024 + j];
      s0 += Wpd[m]*wv; s1 += Wpd[256+m]*wv; s2 += Wpd[512+m]*wv; sb += bpd[m]*wv;
    }
    W3d[j]=s0; W3d[1024+j]=s1; W3d[2048+j]=s2;
    biasD[j] = bih_d[j] + bhh_d[j] + sb;
  }
  if (j < 768) {
    int c = j/3, d = j - c*3;
    float s=0;
    for (int m=0;m<256;++m) s += W2[(size_t)c*256+m]*Wo[m*3+d];
    W2Wo[j] = s;
  }
  if (j < 3) {
    float s = bo[j];
    for (int m=0;m<256;++m) s += b2[m]*Wo[m*3+j];
    b2Wo[j] = s;
  }
}

// ================= generic MFMA GEMM: out(f16) = A @ Wp + bias =================
// tile 64 rows x 256 cols, 4 waves (wave w: cols [w*64, w*64+64)), BK=64
template<bool AF16>
__global__ __launch_bounds__(256) void k_gemm(const void* __restrict__ Ap,
    const f16* __restrict__ Wp, const float* __restrict__ bias,
    f16* __restrict__ out, int K, int Ntot)
{
  __shared__ f16 aLDS[64*64];   // swizzled: slot ^= row&7 (slot = 16B unit)
  const int tid = threadIdx.x, l = tid & 63, w = tid >> 6;
  const int rblk  = blockIdx.x * 64;
  const int cbase = blockIdx.y * 256;
  const int nct   = Ntot >> 4;
  f32x4 acc[4][4];
#pragma unroll
  for (int a=0;a<4;++a)
#pragma unroll
    for (int b=0;b<4;++b) acc[a][b] = (f32x4){0.f,0.f,0.f,0.f};

  const int srow = tid >> 2, sseg = tid & 3;
  for (int kk = 0; kk < K; kk += 64) {
    f16x8 v0, v1;
    if (AF16) {
      const f16* A = (const f16*)Ap + (size_t)(rblk + srow)*K + kk + sseg*16;
      v0 = *(const f16x8*)A;
      v1 = *(const f16x8*)(A+8);
    } else {
      const float* A = (const float*)Ap + (size_t)(rblk + srow)*K + kk + sseg*16;
      float4 f0 = *(const float4*)A,     f1 = *(const float4*)(A+4);
      float4 f2 = *(const float4*)(A+8), f3 = *(const float4*)(A+12);
      v0[0]=(f16)f0.x; v0[1]=(f16)f0.y; v0[2]=(f16)f0.z; v0[3]=(f16)f0.w;
      v0[4]=(f16)f1.x; v0[5]=(f16)f1.y; v0[6]=(f16)f1.z; v0[7]=(f16)f1.w;
      v1[0]=(f16)f2.x; v1[1]=(f16)f2.y; v1[2]=(f16)f2.z; v1[3]=(f16)f2.w;
      v1[4]=(f16)f3.x; v1[5]=(f16)f3.y; v1[6]=(f16)f3.z; v1[7]=(f16)f3.w;
    }
    __syncthreads();           // previous iteration's readers done
    int s0 = sseg*2;
    *(f16x8*)&aLDS[srow*64 + ((s0    ) ^ (srow&7))*8] = v0;
    *(f16x8*)&aLDS[srow*64 + ((s0 + 1) ^ (srow&7))*8] = v1;
    __syncthreads();
    const int kfg0 = kk >> 5;
#pragma unroll
    for (int kf = 0; kf < 2; ++kf) {
      f16x8 afr[4], bfr[4];
#pragma unroll
      for (int rt=0; rt<4; ++rt) {
        int row = rt*16 + (l&15);
        afr[rt] = *(f16x8*)&aLDS[row*64 + (((kf*4) + (l>>4)) ^ (row&7))*8];
      }
#pragma unroll
      for (int ct=0; ct<4; ++ct) {
        int ctg = (cbase>>4) + w*4 + ct;
        bfr[ct] = *(const f16x8*)(Wp + ((size_t)((kfg0+kf)*nct + ctg)*64 + l)*8);
      }
#pragma unroll
      for (int rt=0; rt<4; ++rt)
#pragma unroll
        for (int ct=0; ct<4; ++ct)
          acc[rt][ct] = MFMA16(afr[rt], bfr[ct], acc[rt][ct]);
    }
  }
  // epilogue: D map col=l&15, row=4*(l>>4)+i
#pragma unroll
  for (int ct=0; ct<4; ++ct) {
    int col = cbase + w*64 + ct*16 + (l&15);
    float bv = bias[col];
#pragma unroll
    for (int rt=0; rt<4; ++rt)
#pragma unroll
      for (int i=0;i<4;++i) {
        int r = rblk + rt*16 + ((l>>4)<<2) + i;
        out[(size_t)r*Ntot + col] = (f16)(acc[rt][ct][i] + bv);
      }
  }
}

// ================= recurrent kernels =================
// 64 blocks x 16 rows, 512 threads (8 waves). wave w owns h-cols [w*32, w*32+32):
// ct tiles ctg = q*16 + w*2 + j (q=gate 0..3, j=0..1) -> gate quadruples are lane-local.
// lane cells: hc = w*32 + j*16 + (l&15); rows r = 4*(l>>4)+i.

__global__ __launch_bounds__(512) void k_enc(
    const f16* __restrict__ preg,      // (B*5, 1024)
    const f16* __restrict__ Whh_p,     // packed, nct=64
    const float* __restrict__ W3,      // (3,1024)
    const float* __restrict__ enc_pos, // (B,5,3)
    f16* __restrict__ h_fin, float* __restrict__ c_fin)
{
  __shared__ f16 hLDS[16*256];         // swizzled slot ^= r&7
  __shared__ float W3s[3*1024];
  const int tid = threadIdx.x, l = tid & 63, w = tid >> 6;
  const int rb = blockIdx.x*16;
  for (int i=tid;i<3072;i+=512) W3s[i]=W3[i];
  for (int i=tid;i<2048;i+=512) ((unsigned int*)hLDS)[i]=0u;
  float c_st[2][4]; float hv[2][4];
#pragma unroll
  for (int j=0;j<2;++j)
#pragma unroll
    for (int i=0;i<4;++i){ c_st[j][i]=0.f; hv[j][i]=0.f; }
  __syncthreads();

  for (int t=0;t<5;++t) {
    f32x4 acc[4][2];
#pragma unroll
    for (int q=0;q<4;++q){ acc[q][0]=(f32x4){0,0,0,0}; acc[q][1]=(f32x4){0,0,0,0}; }
#pragma unroll
    for (int kf=0;kf<8;++kf) {
      int row = l&15;
      f16x8 a = *(f16x8*)&hLDS[row*256 + (((kf*4)+(l>>4)) ^ (row&7))*8];
#pragma unroll
      for (int q=0;q<4;++q)
#pragma unroll
        for (int j=0;j<2;++j) {
          int ctg = q*16 + w*2 + j;
          f16x8 b = *(const f16x8*)(Whh_p + ((size_t)(kf*64+ctg)*64 + l)*8);
          acc[q][j] = MFMA16(a, b, acc[q][j]);
        }
    }
    __syncthreads();
#pragma unroll
    for (int i=0;i<4;++i) {
      int r = ((l>>4)<<2) + i;
      int grow = rb + r;
      size_t prow = (size_t)(grow*5 + t)*1024;
      float p0 = enc_pos[(grow*5+t)*3+0];
      float p1 = enc_pos[(grow*5+t)*3+1];
      float p2 = enc_pos[(grow*5+t)*3+2];
#pragma unroll
      for (int j=0;j<2;++j) {
        int hc = w*32 + j*16 + (l&15);
        float gq[4];
#pragma unroll
        for (int q=0;q<4;++q) {
          int gc = q*256 + hc;
          gq[q] = acc[q][j][i] + (float)preg[prow + gc]
                + p0*W3s[gc] + p1*W3s[1024+gc] + p2*W3s[2048+gc];
        }
        float cn = sigm(gq[1])*c_st[j][i] + sigm(gq[0])*tanhf(gq[2]);
        c_st[j][i] = cn;
        float h = sigm(gq[3])*tanhf(cn);
        hv[j][i] = h;
        hLDS[r*256 + (((hc>>3) ^ (r&7))<<3) + (hc&7)] = (f16)h;
      }
    }
    __syncthreads();
  }
#pragma unroll
  for (int i=0;i<4;++i) {
    int r = ((l>>4)<<2) + i;
#pragma unroll
    for (int j=0;j<2;++j) {
      int hc = w*32 + j*16 + (l&15);
      h_fin[(size_t)(rb+r)*256 + hc] = (f16)hv[j][i];
      c_fin[(size_t)(rb+r)*256 + hc] = c_st[j][i];
    }
  }
}

__global__ __launch_bounds__(512) void k_dec(
    const f16* __restrict__ preg,      // (B*25, 1024)
    const f16* __restrict__ Whh_p,
    const float* __restrict__ W3,      // (3,1024)
    const float* __restrict__ dec_pos, // (B,1,3)
    const f16* __restrict__ h_init, const float* __restrict__ c_init,
    const float* __restrict__ W2Wo,    // (256,3)
    const float* __restrict__ b2Wo,    // (3)
    float* __restrict__ out)           // (B,25,3)
{
  __shared__ f16 hLDS[16*256];
  __shared__ float W3s[3*1024];
  __shared__ float W2s[256*3];
  __shared__ float posS[2][16][4];
  __shared__ float dpart[8][16][3];
  const int tid = threadIdx.x, l = tid & 63, w = tid >> 6;
  const int rb = blockIdx.x*16;
  for (int i=tid;i<3072;i+=512) W3s[i]=W3[i];
  for (int i=tid;i<768;i+=512)  W2s[i]=W2Wo[i];
  for (int idx=tid; idx<4096; idx+=512) {
    int r = idx>>8, hc = idx&255;
    hLDS[r*256 + (((hc>>3)^(r&7))<<3) + (hc&7)] = h_init[(size_t)(rb+r)*256 + hc];
  }
  if (tid < 48) { int r=tid/3, k=tid-3*(tid/3); posS[0][r][k] = dec_pos[(size_t)(rb+r)*3 + k]; }
  float c_st[2][4];
#pragma unroll
  for (int j=0;j<2;++j)
#pragma unroll
    for (int i=0;i<4;++i)
      c_st[j][i] = c_init[(size_t)(rb + ((l>>4)<<2)+i)*256 + w*32 + j*16 + (l&15)];
  const float b2w0 = b2Wo[0], b2w1 = b2Wo[1], b2w2 = b2Wo[2];
  __syncthreads();

  int cur = 0;
  for (int t=0;t<25;++t) {
    f32x4 acc[4][2];
#pragma unroll
    for (int q=0;q<4;++q){ acc[q][0]=(f32x4){0,0,0,0}; acc[q][1]=(f32x4){0,0,0,0}; }
#pragma unroll
    for (int kf=0;kf<8;++kf) {
      int row = l&15;
      f16x8 a = *(f16x8*)&hLDS[row*256 + (((kf*4)+(l>>4)) ^ (row&7))*8];
#pragma unroll
      for (int q=0;q<4;++q)
#pragma unroll
        for (int j=0;j<2;++j) {
          int ctg = q*16 + w*2 + j;
          f16x8 b = *(const f16x8*)(Whh_p + ((size_t)(kf*64+ctg)*64 + l)*8);
          acc[q][j] = MFMA16(a, b, acc[q][j]);
        }
    }
    __syncthreads();
    float dpar[4][3];
#pragma unroll
    for (int i=0;i<4;++i){ dpar[i][0]=0.f; dpar[i][1]=0.f; dpar[i][2]=0.f; }
#pragma unroll
    for (int i=0;i<4;++i) {
      int r = ((l>>4)<<2) + i;
      int grow = rb + r;
      size_t prow = (size_t)(grow*25 + t)*1024;
      float p0 = posS[cur][r][0], p1 = posS[cur][r][1], p2 = posS[cur][r][2];
#pragma unroll
      for (int j=0;j<2;++j) {
        int hc = w*32 + j*16 + (l&15);
        float gq[4];
#pragma unroll
        for (int q=0;q<4;++q) {
          int gc = q*256 + hc;
          gq[q] = acc[q][j][i] + (float)preg[prow + gc]
                + p0*W3s[gc] + p1*W3s[1024+gc] + p2*W3s[2048+gc];
        }
        float cn = sigm(gq[1])*c_st[j][i] + sigm(gq[0])*tanhf(gq[2]);
        c_st[j][i] = cn;
        float h = sigm(gq[3])*tanhf(cn);
        hLDS[r*256 + (((hc>>3) ^ (r&7))<<3) + (hc&7)] = (f16)h;
        dpar[i][0] += h*W2s[hc*3+0];
        dpar[i][1] += h*W2s[hc*3+1];
        dpar[i][2] += h*W2s[hc*3+2];
      }
    }
    // reduce delta partials across the 16 lanes of each quarter-wave
#pragma unroll
    for (int m=1;m<16;m<<=1)
#pragma unroll
      for (int i=0;i<4;++i) {
        dpar[i][0] += __shfl_xor(dpar[i][0], m);
        dpar[i][1] += __shfl_xor(dpar[i][1], m);
        dpar[i][2] += __shfl_xor(dpar[i][2], m);
      }
    if ((l&15)==0) {
#pragma unroll
      for (int i=0;i<4;++i) {
        int r = ((l>>4)<<2) + i;
        dpart[w][r][0]=dpar[i][0]; dpart[w][r][1]=dpar[i][1]; dpart[w][r][2]=dpar[i][2];
      }
    }
    __syncthreads();
    if (tid < 16) {
      int r = tid;
      float d0=b2w0, d1=b2w1, d2=b2w2;
#pragma unroll
      for (int ww=0;ww<8;++ww){ d0+=dpart[ww][r][0]; d1+=dpart[ww][r][1]; d2+=dpart[ww][r][2]; }
      float p0 = posS[cur][r][0]+d0, p1 = posS[cur][r][1]+d1, p2 = posS[cur][r][2]+d2;
      float inv = 1.0f/sqrtf(p0*p0+p1*p1+p2*p2);
      p0*=inv; p1*=inv; p2*=inv;
      posS[cur^1][r][0]=p0; posS[cur^1][r][1]=p1; posS[cur^1][r][2]=p2;
      float* o = out + (size_t)(rb+r)*75 + t*3;
      o[0]=p0; o[1]=p1; o[2]=p2;
    }
    cur ^= 1;
    __syncthreads();
  }
}

// ================= launch =================
extern "C" void kernel_launch(void* const* d_in, const int* in_sizes, int n_in,
                              void* d_out, int out_size, void* d_ws, size_t ws_size,
                              hipStream_t stream)
{
  const float* enc_pos = (const float*)d_in[0];
  const float* enc_sal = (const float*)d_in[1];
  const float* dec_pos = (const float*)d_in[2];
  const float* dec_sal = (const float*)d_in[3];
  const float* Wpe  = (const float*)d_in[4];
  const float* bpe  = (const float*)d_in[5];
  const float* Wse  = (const float*)d_in[6];
  const float* bse  = (const float*)d_in[7];
  const float* Wih_e= (const float*)d_in[8];
  const float* Whh_e= (const float*)d_in[9];
  const float* bih_e= (const float*)d_in[10];
  const float* bhh_e= (const float*)d_in[11];
  const float* Wih_d= (const float*)d_in[12];
  const float* Whh_d= (const float*)d_in[13];
  const float* bih_d= (const float*)d_in[14];
  const float* bhh_d= (const float*)d_in[15];
  const float* Wpd  = (const float*)d_in[16];
  const float* bpd  = (const float*)d_in[17];
  const float* Wsd  = (const float*)d_in[18];
  const float* bsd  = (const float*)d_in[19];
  const float* W2   = (const float*)d_in[20];
  const float* b2   = (const float*)d_in[21];
  const float* Wo   = (const float*)d_in[22];
  const float* bo   = (const float*)d_in[23];

  char* ws = (char*)d_ws;
  f16* pWse   = (f16*)(ws + OFF_WSE_P);
  f16* pWsd   = (f16*)(ws + OFF_WSD_P);
  f16* pWih_e = (f16*)(ws + OFF_WIHE_P);
  f16* pWih_d = (f16*)(ws + OFF_WIHD_P);
  f16* pWhh_e = (f16*)(ws + OFF_WHHE_P);
  f16* pWhh_d = (f16*)(ws + OFF_WHHD_P);
  float* W3e  = (float*)(ws + OFF_W3E);
  float* W3d  = (float*)(ws + OFF_W3D);
  float* W2WoP= (float*)(ws + OFF_W2WO);
  float* biasE= (float*)(ws + OFF_BIASE);
  float* biasD= (float*)(ws + OFF_BIASD);
  float* b2WoP= (float*)(ws + OFF_B2WO);
  f16* sal_e  = (f16*)(ws + OFF_SALE);
  f16* sal_d  = (f16*)(ws + OFF_SALD);
  f16* preg_e = (f16*)(ws + OFF_PREGE);
  f16* preg_d = (f16*)(ws + OFF_PREGD);
  f16* h_fin  = (f16*)(ws + OFF_HFIN);
  float* c_fin= (float*)(ws + OFF_CFIN);
  float* out  = (float*)d_out;

  hipLaunchKernelGGL(k_pack_all, dim3(2560), dim3(256), 0, stream,
                     Wse, Wsd, Wih_e, Wih_d, Whh_e, Whh_d,
                     pWse, pWsd, pWih_e, pWih_d, pWhh_e, pWhh_d);
  hipLaunchKernelGGL(k_small, dim3(1), dim3(1024), 0, stream,
                     Wpe, bpe, Wih_e, bih_e, bhh_e,
                     Wpd, bpd, Wih_d, bih_d, bhh_d,
                     W2, b2, Wo, bo,
                     W3e, W3d, biasE, biasD, W2WoP, b2WoP);
  // sal projections (fp32 A, K=8192, N=256)
  hipLaunchKernelGGL((k_gemm<false>), dim3(80,1),  dim3(256), 0, stream,
                     (const void*)enc_sal, pWse, bse, sal_e, 8192, 256);
  hipLaunchKernelGGL((k_gemm<false>), dim3(400,1), dim3(256), 0, stream,
                     (const void*)dec_sal, pWsd, bsd, sal_d, 8192, 256);
  // pre-gate activations (f16 A, K=256, N=1024), bias folded
  hipLaunchKernelGGL((k_gemm<true>),  dim3(80,4),  dim3(256), 0, stream,
                     (const void*)sal_e, pWih_e, biasE, preg_e, 256, 1024);
  hipLaunchKernelGGL((k_gemm<true>),  dim3(400,4), dim3(256), 0, stream,
                     (const void*)sal_d, pWih_d, biasD, preg_d, 256, 1024);
  // recurrences
  hipLaunchKernelGGL(k_enc, dim3(64), dim3(512), 0, stream,
                     preg_e, pWhh_e, W3e, enc_pos, h_fin, c_fin);
  hipLaunchKernelGGL(k_dec, dim3(64), dim3(512), 0, stream,
                     preg_d, pWhh_d, W3d, dec_pos, h_fin, c_fin, W2WoP, b2WoP, out);
}

// Round 2
// 823.263 us; speedup vs baseline: 1.3652x; 1.3652x over previous
//
#include <hip/hip_runtime.h>

typedef _Float16 f16;
typedef _Float16 f16x8 __attribute__((ext_vector_type(8)));
typedef float    f32x4 __attribute__((ext_vector_type(4)));

#define MFMA16(a,b,c) __builtin_amdgcn_mfma_f32_16x16x32_f16((a),(b),(c),0,0,0)

static __device__ __forceinline__ float sigm(float x){ return 1.0f/(1.0f + __expf(-x)); }

// ---------------- workspace layout (bytes) ----------------
static constexpr size_t OFF_WSE_P  = 0;
static constexpr size_t OFF_WSD_P  = OFF_WSE_P  + (size_t)8192*256*2;
static constexpr size_t OFF_WIHE_P = OFF_WSD_P  + (size_t)8192*256*2;
static constexpr size_t OFF_WIHD_P = OFF_WIHE_P + (size_t)256*1024*2;
static constexpr size_t OFF_WHHE_P = OFF_WIHD_P + (size_t)256*1024*2;
static constexpr size_t OFF_WHHD_P = OFF_WHHE_P + (size_t)256*1024*2;
static constexpr size_t OFF_W3E    = OFF_WHHD_P + (size_t)256*1024*2;
static constexpr size_t OFF_W3D    = OFF_W3E   + (size_t)3*1024*4;
static constexpr size_t OFF_W2WO   = OFF_W3D   + (size_t)3*1024*4;
static constexpr size_t OFF_BIASE  = OFF_W2WO  + (size_t)256*3*4;
static constexpr size_t OFF_BIASD  = OFF_BIASE + (size_t)1024*4;
static constexpr size_t OFF_B2WO   = OFF_BIASD + (size_t)1024*4;
static constexpr size_t OFF_SALE   = OFF_B2WO  + 256;
static constexpr size_t OFF_SALD   = OFF_SALE  + (size_t)5120*256*2;
static constexpr size_t OFF_PREGE  = OFF_SALD  + (size_t)25600*256*2;
static constexpr size_t OFF_PREGD  = OFF_PREGE + (size_t)5120*1024*2;
static constexpr size_t OFF_HFIN   = OFF_PREGD + (size_t)25600*1024*2;
static constexpr size_t OFF_CFIN   = OFF_HFIN  + (size_t)1024*256*2;

// ================= pack weights into MFMA B-fragment order =================
// layout [kfg][ctg][lane][8]; element (k,n): k = kfg*32+(l>>4)*8+i, n = ctg*16+(l&15)
__global__ void k_pack_all(const float* __restrict__ Wse, const float* __restrict__ Wsd,
                           const float* __restrict__ Wih_e, const float* __restrict__ Wih_d,
                           const float* __restrict__ Whh_e, const float* __restrict__ Whh_d,
                           f16* pWse, f16* pWsd, f16* pWih_e, f16* pWih_d,
                           f16* pWhh_e, f16* pWhh_d)
{
  int blk = blockIdx.x;
  const float* W; f16* o; int N, base;
  if      (blk < 1024) { W=Wse;   o=pWse;   N=256;  base=0; }
  else if (blk < 2048) { W=Wsd;   o=pWsd;   N=256;  base=1024; }
  else if (blk < 2176) { W=Wih_e; o=pWih_e; N=1024; base=2048; }
  else if (blk < 2304) { W=Wih_d; o=pWih_d; N=1024; base=2176; }
  else if (blk < 2432) { W=Whh_e; o=pWhh_e; N=1024; base=2304; }
  else                 { W=Whh_d; o=pWhh_d; N=1024; base=2432; }
  int tid = (blk - base)*256 + threadIdx.x;
  int l = tid & 63;
  int nct = N >> 4;
  int ctg = (tid >> 6) % nct;
  int kfg = (tid >> 6) / nct;
  int k0  = kfg*32 + ((l>>4)<<3);
  int col = ctg*16 + (l&15);
  f16x8 v;
#pragma unroll
  for (int i=0;i<8;++i) v[i] = (f16)W[(size_t)(k0+i)*N + col];
  *(f16x8*)(o + (size_t)tid*8) = v;
}

// ================= small fused weight products (parallelized) =================
// grid 10 blocks x 256 threads:
// blk 0-3: enc j-chunk; blk 4-7: dec j-chunk; blk 8: W2Wo; blk 9: b2Wo
__global__ __launch_bounds__(256) void k_small(
                        const float* __restrict__ Wpe, const float* __restrict__ bpe,
                        const float* __restrict__ Wih_e, const float* __restrict__ bih_e,
                        const float* __restrict__ bhh_e,
                        const float* __restrict__ Wpd, const float* __restrict__ bpd,
                        const float* __restrict__ Wih_d, const float* __restrict__ bih_d,
                        const float* __restrict__ bhh_d,
                        const float* __restrict__ W2, const float* __restrict__ b2,
                        const float* __restrict__ Wo, const float* __restrict__ bo,
                        float* W3e, float* W3d, float* biasE, float* biasD,
                        float* W2Wo, float* b2Wo)
{
  int bid = blockIdx.x, tid = threadIdx.x;
  if (bid < 4) {
    int j = bid*256 + tid;
    float s0=0,s1=0,s2=0,sb=0;
    for (int m=0;m<256;++m) {
      float wv = Wih_e[(size_t)(256+m)*1024 + j];
      s0 += Wpe[m]*wv; s1 += Wpe[256+m]*wv; s2 += Wpe[512+m]*wv; sb += bpe[m]*wv;
    }
    W3e[j]=s0; W3e[1024+j]=s1; W3e[2048+j]=s2;
    biasE[j] = bih_e[j] + bhh_e[j] + sb;
  } else if (bid < 8) {
    int j = (bid-4)*256 + tid;
    float s0=0,s1=0,s2=0,sb=0;
    for (int m=0;m<256;++m) {
      float wv = Wih_d[(size_t)(256+m)*1024 + j];
      s0 += Wpd[m]*wv; s1 += Wpd[256+m]*wv; s2 += Wpd[512+m]*wv; sb += bpd[m]*wv;
    }
    W3d[j]=s0; W3d[1024+j]=s1; W3d[2048+j]=s2;
    biasD[j] = bih_d[j] + bhh_d[j] + sb;
  } else if (bid == 8) {
    int c = tid;   // 256 threads, one h-col each; W2 row contiguous
    float s0=0,s1=0,s2=0;
    for (int m=0;m<256;++m) {
      float wv = W2[(size_t)c*256+m];
      s0 += wv*Wo[m*3+0]; s1 += wv*Wo[m*3+1]; s2 += wv*Wo[m*3+2];
    }
    W2Wo[c*3+0]=s0; W2Wo[c*3+1]=s1; W2Wo[c*3+2]=s2;
  } else {
    if (tid < 192) {
      int j = tid >> 6, lane = tid & 63;
      float s = 0.f;
      for (int m=lane;m<256;m+=64) s += b2[m]*Wo[m*3+j];
#pragma unroll
      for (int msk=1;msk<64;msk<<=1) s += __shfl_xor(s, msk);
      if (lane==0) b2Wo[j] = s + bo[j];
    }
  }
}

// ================= pipelined MFMA GEMM: out(f16) = A @ Wp + bias ============
// tile 64 rows x 256 cols, 4 waves (wave w: cols [w*64,+64)), BK=64
// reg-prefetch of next A tile issued BEFORE compute; LDS double-buffered.
// merged: blocks [0,nb0) = job0, [nb0,..) = job1
template<int K, bool AF16>
__global__ __launch_bounds__(256) void k_gemm2(
    const void* __restrict__ A0, const f16* __restrict__ W0,
    const float* __restrict__ b0, f16* __restrict__ o0, int nb0,
    const void* __restrict__ A1, const f16* __restrict__ W1,
    const float* __restrict__ b1, f16* __restrict__ o1, int Ntot)
{
  __shared__ f16 aLDS[2][64*64];   // swizzled: slot ^= row&7 (slot = 16B unit)
  const int tid = threadIdx.x, l = tid & 63, w = tid >> 6;
  const int bx = blockIdx.x;
  const void* Ap; const f16* Wp; const float* bias; f16* out; int rblk;
  if (bx < nb0) { Ap=A0; Wp=W0; bias=b0; out=o0; rblk = bx*64; }
  else          { Ap=A1; Wp=W1; bias=b1; out=o1; rblk = (bx-nb0)*64; }
  const int cbase = blockIdx.y * 256;
  const int nct   = Ntot >> 4;
  f32x4 acc[4][4];
#pragma unroll
  for (int a=0;a<4;++a)
#pragma unroll
    for (int b=0;b<4;++b) acc[a][b] = (f32x4){0.f,0.f,0.f,0.f};

  const int srow = tid >> 2, sseg = tid & 3;
  float4 f0,f1,f2,f3; f16x8 v0,v1;
#define LOADF(kk_) { const float* Aq = (const float*)Ap + (size_t)(rblk+srow)*K + (kk_) + sseg*16; \
    f0 = *(const float4*)Aq; f1 = *(const float4*)(Aq+4);                                         \
    f2 = *(const float4*)(Aq+8); f3 = *(const float4*)(Aq+12); }
#define LOADH(kk_) { const f16* Aq = (const f16*)Ap + (size_t)(rblk+srow)*K + (kk_) + sseg*16;    \
    v0 = *(const f16x8*)Aq; v1 = *(const f16x8*)(Aq+8); }
  if constexpr (AF16) { LOADH(0); } else { LOADF(0); }

  for (int kk = 0; kk < K; kk += 64) {
    const int buf = (kk>>6)&1;
    __syncthreads();                       // readers of this buf (iter kk-2) done
    f16x8 w0, w1;
    if constexpr (AF16) { w0 = v0; w1 = v1; }
    else {
      w0[0]=(f16)f0.x; w0[1]=(f16)f0.y; w0[2]=(f16)f0.z; w0[3]=(f16)f0.w;
      w0[4]=(f16)f1.x; w0[5]=(f16)f1.y; w0[6]=(f16)f1.z; w0[7]=(f16)f1.w;
      w1[0]=(f16)f2.x; w1[1]=(f16)f2.y; w1[2]=(f16)f2.z; w1[3]=(f16)f2.w;
      w1[4]=(f16)f3.x; w1[5]=(f16)f3.y; w1[6]=(f16)f3.z; w1[7]=(f16)f3.w;
    }
    const int s0i = sseg*2;
    *(f16x8*)&aLDS[buf][srow*64 + ((s0i    ) ^ (srow&7))*8] = w0;
    *(f16x8*)&aLDS[buf][srow*64 + ((s0i + 1) ^ (srow&7))*8] = w1;
    {  // prefetch next tile BEFORE compute — HBM latency hides under MFMA phase
      const int kn = (kk + 64 < K) ? (kk + 64) : kk;
      if constexpr (AF16) { LOADH(kn); } else { LOADF(kn); }
    }
    __syncthreads();
    const int kfg0 = kk >> 5;
#pragma unroll
    for (int kf = 0; kf < 2; ++kf) {
      f16x8 afr[4], bfr[4];
#pragma unroll
      for (int ct=0; ct<4; ++ct) {
        int ctg = (cbase>>4) + w*4 + ct;
        bfr[ct] = *(const f16x8*)(Wp + ((size_t)((kfg0+kf)*nct + ctg)*64 + l)*8);
      }
#pragma unroll
      for (int rt=0; rt<4; ++rt) {
        int row = rt*16 + (l&15);
        afr[rt] = *(f16x8*)&aLDS[buf][row*64 + (((kf*4) + (l>>4)) ^ (row&7))*8];
      }
#pragma unroll
      for (int rt=0; rt<4; ++rt)
#pragma unroll
        for (int ct=0; ct<4; ++ct)
          acc[rt][ct] = MFMA16(afr[rt], bfr[ct], acc[rt][ct]);
    }
  }
#undef LOADF
#undef LOADH
  // epilogue: D map col=l&15, row=4*(l>>4)+i
#pragma unroll
  for (int ct=0; ct<4; ++ct) {
    int col = cbase + w*64 + ct*16 + (l&15);
    float bv = bias[col];
#pragma unroll
    for (int rt=0; rt<4; ++rt)
#pragma unroll
      for (int i=0;i<4;++i) {
        int r = rblk + rt*16 + ((l>>4)<<2) + i;
        out[(size_t)r*Ntot + col] = (f16)(acc[rt][ct][i] + bv);
      }
  }
}

// ================= recurrent kernels =================
// 64 blocks x 16 rows, 512 threads (8 waves). wave w owns h-cols [w*32, w*32+32):
// ct tiles ctg = q*16 + w*2 + j (q=gate 0..3, j=0..1) -> gate quadruples lane-local.
// lane cells: hc = w*32 + j*16 + (l&15); rows r = 4*(l>>4)+i.

__global__ __launch_bounds__(512) void k_enc(
    const f16* __restrict__ preg,      // (B*5, 1024)
    const f16* __restrict__ Whh_p,     // packed, nct=64
    const float* __restrict__ W3,      // (3,1024)
    const float* __restrict__ enc_pos, // (B,5,3)
    f16* __restrict__ h_fin, float* __restrict__ c_fin)
{
  __shared__ f16 hLDS[16*256];         // swizzled slot ^= r&7
  __shared__ float W3s[3*1024];
  const int tid = threadIdx.x, l = tid & 63, w = tid >> 6;
  const int rb = blockIdx.x*16;
  for (int i=tid;i<3072;i+=512) W3s[i]=W3[i];
  for (int i=tid;i<2048;i+=512) ((unsigned int*)hLDS)[i]=0u;
  float c_st[2][4]; float hv[2][4];
#pragma unroll
  for (int j=0;j<2;++j)
#pragma unroll
    for (int i=0;i<4;++i){ c_st[j][i]=0.f; hv[j][i]=0.f; }
  __syncthreads();

  for (int t=0;t<5;++t) {
    // ---- hoisted global loads: issue before MFMA phase, consume after barrier
    f16 pv[4][2][4]; float pp[4][3];
#pragma unroll
    for (int i=0;i<4;++i) {
      int grow = rb + ((l>>4)<<2) + i;
      const f16* pr = preg + (size_t)(grow*5 + t)*1024;
#pragma unroll
      for (int j=0;j<2;++j) {
        int hc = w*32 + j*16 + (l&15);
#pragma unroll
        for (int q=0;q<4;++q) pv[i][j][q] = pr[q*256 + hc];
      }
      pp[i][0]=enc_pos[(grow*5+t)*3+0]; pp[i][1]=enc_pos[(grow*5+t)*3+1]; pp[i][2]=enc_pos[(grow*5+t)*3+2];
    }
    f32x4 acc[4][2];
#pragma unroll
    for (int q=0;q<4;++q){ acc[q][0]=(f32x4){0,0,0,0}; acc[q][1]=(f32x4){0,0,0,0}; }
#pragma unroll
    for (int kf=0;kf<8;++kf) {
      int row = l&15;
      f16x8 a = *(f16x8*)&hLDS[row*256 + (((kf*4)+(l>>4)) ^ (row&7))*8];
#pragma unroll
      for (int q=0;q<4;++q)
#pragma unroll
        for (int j=0;j<2;++j) {
          int ctg = q*16 + w*2 + j;
          f16x8 b = *(const f16x8*)(Whh_p + ((size_t)(kf*64+ctg)*64 + l)*8);
          acc[q][j] = MFMA16(a, b, acc[q][j]);
        }
    }
    __syncthreads();
#pragma unroll
    for (int i=0;i<4;++i) {
      int r = ((l>>4)<<2) + i;
      float p0 = pp[i][0], p1 = pp[i][1], p2 = pp[i][2];
#pragma unroll
      for (int j=0;j<2;++j) {
        int hc = w*32 + j*16 + (l&15);
        float gq[4];
#pragma unroll
        for (int q=0;q<4;++q) {
          int gc = q*256 + hc;
          gq[q] = acc[q][j][i] + (float)pv[i][j][q]
                + p0*W3s[gc] + p1*W3s[1024+gc] + p2*W3s[2048+gc];
        }
        float cn = sigm(gq[1])*c_st[j][i] + sigm(gq[0])*tanhf(gq[2]);
        c_st[j][i] = cn;
        float h = sigm(gq[3])*tanhf(cn);
        hv[j][i] = h;
        hLDS[r*256 + (((hc>>3) ^ (r&7))<<3) + (hc&7)] = (f16)h;
      }
    }
    __syncthreads();
  }
#pragma unroll
  for (int i=0;i<4;++i) {
    int r = ((l>>4)<<2) + i;
#pragma unroll
    for (int j=0;j<2;++j) {
      int hc = w*32 + j*16 + (l&15);
      h_fin[(size_t)(rb+r)*256 + hc] = (f16)hv[j][i];
      c_fin[(size_t)(rb+r)*256 + hc] = c_st[j][i];
    }
  }
}

__global__ __launch_bounds__(512) void k_dec(
    const f16* __restrict__ preg,      // (B*25, 1024)
    const f16* __restrict__ Whh_p,
    const float* __restrict__ W3,      // (3,1024)
    const float* __restrict__ dec_pos, // (B,1,3)
    const f16* __restrict__ h_init, const float* __restrict__ c_init,
    const float* __restrict__ W2Wo,    // (256,3)
    const float* __restrict__ b2Wo,    // (3)
    float* __restrict__ out)           // (B,25,3)
{
  __shared__ f16 hLDS[16*256];
  __shared__ float W3s[3*1024];
  __shared__ float W2s[256*3];
  __shared__ float posS[2][16][4];
  __shared__ float dpart[8][16][3];
  const int tid = threadIdx.x, l = tid & 63, w = tid >> 6;
  const int rb = blockIdx.x*16;
  for (int i=tid;i<3072;i+=512) W3s[i]=W3[i];
  for (int i=tid;i<768;i+=512)  W2s[i]=W2Wo[i];
  for (int idx=tid; idx<4096; idx+=512) {
    int r = idx>>8, hc = idx&255;
    hLDS[r*256 + (((hc>>3)^(r&7))<<3) + (hc&7)] = h_init[(size_t)(rb+r)*256 + hc];
  }
  if (tid < 48) { int r=tid/3, k=tid-3*(tid/3); posS[0][r][k] = dec_pos[(size_t)(rb+r)*3 + k]; }
  float c_st[2][4];
#pragma unroll
  for (int j=0;j<2;++j)
#pragma unroll
    for (int i=0;i<4;++i)
      c_st[j][i] = c_init[(size_t)(rb + ((l>>4)<<2)+i)*256 + w*32 + j*16 + (l&15)];
  const float b2w0 = b2Wo[0], b2w1 = b2Wo[1], b2w2 = b2Wo[2];
  __syncthreads();

  int cur = 0;
  for (int t=0;t<25;++t) {
    // ---- hoisted preg loads (independent of recurrence) ----
    f16 pv[4][2][4];
#pragma unroll
    for (int i=0;i<4;++i) {
      int grow = rb + ((l>>4)<<2) + i;
      const f16* pr = preg + (size_t)(grow*25 + t)*1024;
#pragma unroll
      for (int j=0;j<2;++j) {
        int hc = w*32 + j*16 + (l&15);
#pragma unroll
        for (int q=0;q<4;++q) pv[i][j][q] = pr[q*256 + hc];
      }
    }
    f32x4 acc[4][2];
#pragma unroll
    for (int q=0;q<4;++q){ acc[q][0]=(f32x4){0,0,0,0}; acc[q][1]=(f32x4){0,0,0,0}; }
#pragma unroll
    for (int kf=0;kf<8;++kf) {
      int row = l&15;
      f16x8 a = *(f16x8*)&hLDS[row*256 + (((kf*4)+(l>>4)) ^ (row&7))*8];
#pragma unroll
      for (int q=0;q<4;++q)
#pragma unroll
        for (int j=0;j<2;++j) {
          int ctg = q*16 + w*2 + j;
          f16x8 b = *(const f16x8*)(Whh_p + ((size_t)(kf*64+ctg)*64 + l)*8);
          acc[q][j] = MFMA16(a, b, acc[q][j]);
        }
    }
    __syncthreads();
    float dpar[4][3];
#pragma unroll
    for (int i=0;i<4;++i){ dpar[i][0]=0.f; dpar[i][1]=0.f; dpar[i][2]=0.f; }
#pragma unroll
    for (int i=0;i<4;++i) {
      int r = ((l>>4)<<2) + i;
      float p0 = posS[cur][r][0], p1 = posS[cur][r][1], p2 = posS[cur][r][2];
#pragma unroll
      for (int j=0;j<2;++j) {
        int hc = w*32 + j*16 + (l&15);
        float gq[4];
#pragma unroll
        for (int q=0;q<4;++q) {
          int gc = q*256 + hc;
          gq[q] = acc[q][j][i] + (float)pv[i][j][q]
                + p0*W3s[gc] + p1*W3s[1024+gc] + p2*W3s[2048+gc];
        }
        float cn = sigm(gq[1])*c_st[j][i] + sigm(gq[0])*tanhf(gq[2]);
        c_st[j][i] = cn;
        float h = sigm(gq[3])*tanhf(cn);
        hLDS[r*256 + (((hc>>3) ^ (r&7))<<3) + (hc&7)] = (f16)h;
        dpar[i][0] += h*W2s[hc*3+0];
        dpar[i][1] += h*W2s[hc*3+1];
        dpar[i][2] += h*W2s[hc*3+2];
      }
    }
#pragma unroll
    for (int m=1;m<16;m<<=1)
#pragma unroll
      for (int i=0;i<4;++i) {
        dpar[i][0] += __shfl_xor(dpar[i][0], m);
        dpar[i][1] += __shfl_xor(dpar[i][1], m);
        dpar[i][2] += __shfl_xor(dpar[i][2], m);
      }
    if ((l&15)==0) {
#pragma unroll
      for (int i=0;i<4;++i) {
        int r = ((l>>4)<<2) + i;
        dpart[w][r][0]=dpar[i][0]; dpart[w][r][1]=dpar[i][1]; dpart[w][r][2]=dpar[i][2];
      }
    }
    __syncthreads();
    if (tid < 16) {
      int r = tid;
      float d0=b2w0, d1=b2w1, d2=b2w2;
#pragma unroll
      for (int ww=0;ww<8;++ww){ d0+=dpart[ww][r][0]; d1+=dpart[ww][r][1]; d2+=dpart[ww][r][2]; }
      float p0 = posS[cur][r][0]+d0, p1 = posS[cur][r][1]+d1, p2 = posS[cur][r][2]+d2;
      float inv = 1.0f/sqrtf(p0*p0+p1*p1+p2*p2);
      p0*=inv; p1*=inv; p2*=inv;
      posS[cur^1][r][0]=p0; posS[cur^1][r][1]=p1; posS[cur^1][r][2]=p2;
      float* o = out + (size_t)(rb+r)*75 + t*3;
      o[0]=p0; o[1]=p1; o[2]=p2;
    }
    cur ^= 1;
    __syncthreads();
  }
}

// ================= launch =================
extern "C" void kernel_launch(void* const* d_in, const int* in_sizes, int n_in,
                              void* d_out, int out_size, void* d_ws, size_t ws_size,
                              hipStream_t stream)
{
  const float* enc_pos = (const float*)d_in[0];
  const float* enc_sal = (const float*)d_in[1];
  const float* dec_pos = (const float*)d_in[2];
  const float* dec_sal = (const float*)d_in[3];
  const float* Wpe  = (const float*)d_in[4];
  const float* bpe  = (const float*)d_in[5];
  const float* Wse  = (const float*)d_in[6];
  const float* bse  = (const float*)d_in[7];
  const float* Wih_e= (const float*)d_in[8];
  const float* Whh_e= (const float*)d_in[9];
  const float* bih_e= (const float*)d_in[10];
  const float* bhh_e= (const float*)d_in[11];
  const float* Wih_d= (const float*)d_in[12];
  const float* Whh_d= (const float*)d_in[13];
  const float* bih_d= (const float*)d_in[14];
  const float* bhh_d= (const float*)d_in[15];
  const float* Wpd  = (const float*)d_in[16];
  const float* bpd  = (const float*)d_in[17];
  const float* Wsd  = (const float*)d_in[18];
  const float* bsd  = (const float*)d_in[19];
  const float* W2   = (const float*)d_in[20];
  const float* b2   = (const float*)d_in[21];
  const float* Wo   = (const float*)d_in[22];
  const float* bo   = (const float*)d_in[23];

  char* ws = (char*)d_ws;
  f16* pWse   = (f16*)(ws + OFF_WSE_P);
  f16* pWsd   = (f16*)(ws + OFF_WSD_P);
  f16* pWih_e = (f16*)(ws + OFF_WIHE_P);
  f16* pWih_d = (f16*)(ws + OFF_WIHD_P);
  f16* pWhh_e = (f16*)(ws + OFF_WHHE_P);
  f16* pWhh_d = (f16*)(ws + OFF_WHHD_P);
  float* W3e  = (float*)(ws + OFF_W3E);
  float* W3d  = (float*)(ws + OFF_W3D);
  float* W2WoP= (float*)(ws + OFF_W2WO);
  float* biasE= (float*)(ws + OFF_BIASE);
  float* biasD= (float*)(ws + OFF_BIASD);
  float* b2WoP= (float*)(ws + OFF_B2WO);
  f16* sal_e  = (f16*)(ws + OFF_SALE);
  f16* sal_d  = (f16*)(ws + OFF_SALD);
  f16* preg_e = (f16*)(ws + OFF_PREGE);
  f16* preg_d = (f16*)(ws + OFF_PREGD);
  f16* h_fin  = (f16*)(ws + OFF_HFIN);
  float* c_fin= (float*)(ws + OFF_CFIN);
  float* out  = (float*)d_out;

  hipLaunchKernelGGL(k_pack_all, dim3(2560), dim3(256), 0, stream,
                     Wse, Wsd, Wih_e, Wih_d, Whh_e, Whh_d,
                     pWse, pWsd, pWih_e, pWih_d, pWhh_e, pWhh_d);
  hipLaunchKernelGGL(k_small, dim3(10), dim3(256), 0, stream,
                     Wpe, bpe, Wih_e, bih_e, bhh_e,
                     Wpd, bpd, Wih_d, bih_d, bhh_d,
                     W2, b2, Wo, bo,
                     W3e, W3d, biasE, biasD, W2WoP, b2WoP);
  // sal projections (fp32 A, K=8192, N=256): enc blocks [0,80), dec [80,480)
  hipLaunchKernelGGL((k_gemm2<8192,false>), dim3(480,1), dim3(256), 0, stream,
                     (const void*)enc_sal, pWse, bse, sal_e, 80,
                     (const void*)dec_sal, pWsd, bsd, sal_d, 256);
  // pre-gate activations (f16 A, K=256, N=1024), bias folded
  hipLaunchKernelGGL((k_gemm2<256,true>),  dim3(480,4), dim3(256), 0, stream,
                     (const void*)sal_e, pWih_e, biasE, preg_e, 80,
                     (const void*)sal_d, pWih_d, biasD, preg_d, 1024);
  // recurrences
  hipLaunchKernelGGL(k_enc, dim3(64), dim3(512), 0, stream,
                     preg_e, pWhh_e, W3e, enc_pos, h_fin, c_fin);
  hipLaunchKernelGGL(k_dec, dim3(64), dim3(512), 0, stream,
                     preg_d, pWhh_d, W3d, dec_pos, h_fin, c_fin, W2WoP, b2WoP, out);
}